// Round 2
// baseline (783.005 us; speedup 1.0000x reference)
//
#include <hip/hip_runtime.h>
#include <stdint.h>

#define NVOX 262144
#define CIN  128
#define KOFF 27

typedef short  bf16x8 __attribute__((ext_vector_type(8)));
typedef float  f32x4  __attribute__((ext_vector_type(4)));

__device__ __forceinline__ unsigned short f2bf(float x) {
    unsigned int u = __builtin_bit_cast(unsigned int, x);
    u += 0x7fff + ((u >> 16) & 1);           // round-to-nearest-even
    return (unsigned short)(u >> 16);
}

// ---- detect mask dtype: int32 (all of first 256 words in {0,1}) vs byte ----
__global__ void k_detect(const int* __restrict__ mask_i32, int* __restrict__ flag) {
    bool ok = true;
    for (int i = threadIdx.x; i < 256; i += 64) {
        int v = mask_i32[i];
        ok = ok && (v == 0 || v == 1);
    }
    unsigned long long b = __ballot(ok);
    if (threadIdx.x == 0) *flag = (b == ~0ull) ? 1 : 0;
}

// ---- fold mask into neighbor list: nbr_eff = mask ? nbr : -1 ----
__global__ __launch_bounds__(256) void k_prepnbr(
    const int* __restrict__ nbr, const void* __restrict__ mask,
    const int* __restrict__ flag, int* __restrict__ nbr_eff, int total) {
    int i = blockIdx.x * 256 + threadIdx.x;
    if (i >= total) return;
    bool mk;
    if (*flag) mk = ((const int*)mask)[i] != 0;
    else       mk = ((const unsigned char*)mask)[i] != 0;
    nbr_eff[i] = mk ? nbr[i] : -1;
}

// ---------------- prep: x (f32) -> xb (bf16), 8 elems/thread ----------------
__global__ __launch_bounds__(256) void k_convert(const float* __restrict__ x,
                                                 uint4* __restrict__ xb) {
    int i = blockIdx.x * 256 + threadIdx.x;          // one uint4 (8 bf16) out
    const float4* p = (const float4*)x + (size_t)i * 2;
    float4 a = p[0], b = p[1];
    uint4 r;
    r.x = f2bf(a.x) | ((unsigned)f2bf(a.y) << 16);
    r.y = f2bf(a.z) | ((unsigned)f2bf(a.w) << 16);
    r.z = f2bf(b.x) | ((unsigned)f2bf(b.y) << 16);
    r.w = f2bf(b.z) | ((unsigned)f2bf(b.w) << 16);
    xb[i] = r;
}

// ---------------- prep: pack weight [G,K,Nc] f32 -> MFMA B-frag bf16 --------
// frag f = (g*(K/32)+kc)*(Nc/16)+nt ; out[f*512 + lane*8 + j] =
//   W[g][kc*32 + (lane>>4)*8 + j][nt*16 + (lane&15)]
__global__ __launch_bounds__(256) void k_pack(const float* __restrict__ W,
                                              unsigned short* __restrict__ out,
                                              int G, int K, int Nc) {
    int idx = blockIdx.x * 256 + threadIdx.x;
    int total = G * K * Nc;
    if (idx >= total) return;
    int j    = idx & 7;
    int lane = (idx >> 3) & 63;
    int f    = idx >> 9;
    int ntiles = Nc >> 4, kcs = K >> 5;
    int g  = f / (kcs * ntiles);
    int rem = f - g * (kcs * ntiles);
    int kc = rem / ntiles;
    int nt = rem - kc * ntiles;
    int k  = kc * 32 + ((lane >> 4) << 3) + j;
    int n  = nt * 16 + (lane & 15);
    out[idx] = f2bf(W[((size_t)g * K + k) * Nc + n]);
}

// ---------------- kernel A: s = [relu(conv00(x)+b00) | relu(x@W10+b10)] -----
// block: 64 voxels, 4 waves x 16 voxels; s_out: [N][64] bf16
__global__ __launch_bounds__(256) void k_convA(
    const unsigned short* __restrict__ xb,
    const int* __restrict__ nbr_eff,
    const unsigned short* __restrict__ w00, const unsigned short* __restrict__ w10,
    const float* __restrict__ b00, const float* __restrict__ b10,
    unsigned short* __restrict__ s_out)
{
    __shared__ int nbr_s[64 * 27];
    __shared__ unsigned short stage[64 * 72];        // pad 64->72 vs bank conflicts

    int tid = threadIdx.x;
    int vb  = blockIdx.x * 64;
    for (int i = tid; i < 64 * 27; i += 256)
        nbr_s[i] = nbr_eff[(size_t)vb * 27 + i];
    __syncthreads();

    int lane = tid & 63, wave = tid >> 6;
    int m = lane & 15, q = lane >> 4;
    int vl = wave * 16 + m;                          // local voxel (A row)

    f32x4 t0 = {0.f,0.f,0.f,0.f}, t1 = t0, u0 = t0, u1 = t0;

    for (int ko = 0; ko < 27; ++ko) {
        int j = nbr_s[vl * 27 + ko];
        bool mk = j >= 0;
        if (__ballot(mk) == 0ull) continue;
        const bf16x8* xrow = (const bf16x8*)(xb + (size_t)(mk ? j : 0) * 128 + q * 8);
        const bf16x8* wp   = (const bf16x8*)(w00) + (size_t)ko * 8 * 64 + lane;
#pragma unroll
        for (int kc = 0; kc < 4; ++kc) {
            bf16x8 a = {0,0,0,0,0,0,0,0};
            if (mk) a = xrow[kc * 4];                // 16B gather, masked
            bf16x8 bb0 = wp[kc * 128];
            bf16x8 bb1 = wp[kc * 128 + 64];
            t0 = __builtin_amdgcn_mfma_f32_16x16x32_bf16(a, bb0, t0, 0, 0, 0);
            t1 = __builtin_amdgcn_mfma_f32_16x16x32_bf16(a, bb1, t1, 0, 0, 0);
            if (ko == 13) {                          // center offset == own row
                const bf16x8* wq = (const bf16x8*)(w10) + lane;
                bf16x8 c0 = wq[kc * 128];
                bf16x8 c1 = wq[kc * 128 + 64];
                u0 = __builtin_amdgcn_mfma_f32_16x16x32_bf16(a, c0, u0, 0, 0, 0);
                u1 = __builtin_amdgcn_mfma_f32_16x16x32_bf16(a, c1, u1, 0, 0, 0);
            }
        }
    }

    // epilogue: bias + relu -> bf16 via LDS transpose, coalesced store
    int col = lane & 15;
    float bt0 = b00[col], bt1 = b00[16 + col];
    float bu0 = b10[col], bu1 = b10[16 + col];
#pragma unroll
    for (int r = 0; r < 4; ++r) {
        int row = wave * 16 + q * 4 + r;
        unsigned short* sp = stage + row * 72;
        sp[col]      = f2bf(fmaxf(t0[r] + bt0, 0.f));
        sp[16 + col] = f2bf(fmaxf(t1[r] + bt1, 0.f));
        sp[32 + col] = f2bf(fmaxf(u0[r] + bu0, 0.f));
        sp[48 + col] = f2bf(fmaxf(u1[r] + bu1, 0.f));
    }
    __syncthreads();
    uint4* g4 = (uint4*)(s_out + (size_t)vb * 64);
    for (int i = tid; i < 512; i += 256) {
        int row = i >> 3, c = i & 7;
        g4[row * 8 + c] = *(const uint4*)(stage + row * 72 + c * 8);
    }
}

// ---------------- kernel B: out = [conv01(t)+b01 | relu(conv11(u)+b11)@W12+b12] + x
__global__ __launch_bounds__(256) void k_convB(
    const unsigned short* __restrict__ s_in,
    const float* __restrict__ x,
    const int* __restrict__ nbr_eff,
    const unsigned short* __restrict__ w01, const unsigned short* __restrict__ w11,
    const unsigned short* __restrict__ w12,
    const float* __restrict__ b01, const float* __restrict__ b11,
    const float* __restrict__ b12,
    float* __restrict__ out)
{
    __shared__ int nbr_s[64 * 27];
    __shared__ unsigned short vstage[4][16 * 40];    // per-wave v (16x32, pad 40)
    __shared__ float ostage[64 * 136];               // 64 voxels x 128ch, pad 136

    int tid = threadIdx.x;
    int vb  = blockIdx.x * 64;
    for (int i = tid; i < 64 * 27; i += 256)
        nbr_s[i] = nbr_eff[(size_t)vb * 27 + i];
    __syncthreads();

    int lane = tid & 63, wave = tid >> 6;
    int m = lane & 15, q = lane >> 4;
    int vl = wave * 16 + m;

    f32x4 o0 = {0.f,0.f,0.f,0.f}, o1 = o0, o2 = o0, o3 = o0, v0 = o0, v1 = o0;

    for (int ko = 0; ko < 27; ++ko) {
        int j = nbr_s[vl * 27 + ko];
        bool mk = j >= 0;
        if (__ballot(mk) == 0ull) continue;
        bf16x8 at = {0,0,0,0,0,0,0,0}, au = at;
        if (mk) {
            const bf16x8* srow = (const bf16x8*)(s_in + (size_t)j * 64 + q * 8);
            at = srow[0];                            // t part (ch 0..31)
            au = srow[4];                            // u part (ch 32..63)
        }
        const bf16x8* wp1 = (const bf16x8*)(w01) + (size_t)ko * 4 * 64 + lane;
        o0 = __builtin_amdgcn_mfma_f32_16x16x32_bf16(at, wp1[0],   o0, 0, 0, 0);
        o1 = __builtin_amdgcn_mfma_f32_16x16x32_bf16(at, wp1[64],  o1, 0, 0, 0);
        o2 = __builtin_amdgcn_mfma_f32_16x16x32_bf16(at, wp1[128], o2, 0, 0, 0);
        o3 = __builtin_amdgcn_mfma_f32_16x16x32_bf16(at, wp1[192], o3, 0, 0, 0);
        const bf16x8* wp2 = (const bf16x8*)(w11) + (size_t)ko * 2 * 64 + lane;
        v0 = __builtin_amdgcn_mfma_f32_16x16x32_bf16(au, wp2[0],   v0, 0, 0, 0);
        v1 = __builtin_amdgcn_mfma_f32_16x16x32_bf16(au, wp2[64],  v1, 0, 0, 0);
    }

    // v = relu(v + b11): C-layout -> A-layout via LDS round-trip
    int col = lane & 15;
    {
        float bv0 = b11[col], bv1 = b11[16 + col];
        unsigned short* vs = vstage[wave];
#pragma unroll
        for (int r = 0; r < 4; ++r) {
            int row = q * 4 + r;
            vs[row * 40 + col]      = f2bf(fmaxf(v0[r] + bv0, 0.f));
            vs[row * 40 + 16 + col] = f2bf(fmaxf(v1[r] + bv1, 0.f));
        }
    }
    __syncthreads();
    bf16x8 av = *(const bf16x8*)(vstage[wave] + m * 40 + q * 8);
    const bf16x8* wp3 = (const bf16x8*)(w12) + lane;
    f32x4 z = {0.f,0.f,0.f,0.f};
    f32x4 o4 = __builtin_amdgcn_mfma_f32_16x16x32_bf16(av, wp3[0],   z, 0, 0, 0);
    f32x4 o5 = __builtin_amdgcn_mfma_f32_16x16x32_bf16(av, wp3[64],  z, 0, 0, 0);
    f32x4 o6 = __builtin_amdgcn_mfma_f32_16x16x32_bf16(av, wp3[128], z, 0, 0, 0);
    f32x4 o7 = __builtin_amdgcn_mfma_f32_16x16x32_bf16(av, wp3[192], z, 0, 0, 0);

    // stage full 64x128 f32 tile, then coalesced add-x + store
#pragma unroll
    for (int r = 0; r < 4; ++r) {
        int row = wave * 16 + q * 4 + r;
        float* op = ostage + row * 136;
        op[col]       = o0[r] + b01[col];
        op[16 + col]  = o1[r] + b01[16 + col];
        op[32 + col]  = o2[r] + b01[32 + col];
        op[48 + col]  = o3[r] + b01[48 + col];
        op[64 + col]  = o4[r] + b12[col];
        op[80 + col]  = o5[r] + b12[16 + col];
        op[96 + col]  = o6[r] + b12[32 + col];
        op[112 + col] = o7[r] + b12[48 + col];
    }
    __syncthreads();
    for (int i = tid; i < 2048; i += 256) {
        int row = i >> 5, c4 = i & 31;
        const float* sp = ostage + row * 136 + c4 * 4;
        size_t go = ((size_t)(vb + row)) * 128 + c4 * 4;
        float4 xv = *(const float4*)(x + go);
        float4 r;
        r.x = sp[0] + xv.x; r.y = sp[1] + xv.y;
        r.z = sp[2] + xv.z; r.w = sp[3] + xv.w;
        *(float4*)(out + go) = r;
    }
}

extern "C" void kernel_launch(void* const* d_in, const int* in_sizes, int n_in,
                              void* d_out, int out_size, void* d_ws, size_t ws_size,
                              hipStream_t stream) {
    const float* x   = (const float*)d_in[0];
    const int*   nbr = (const int*)d_in[1];
    const void*  mask = d_in[2];                      // dtype detected at runtime
    const float* W00 = (const float*)d_in[3];
    const float* b00 = (const float*)d_in[4];
    const float* W01 = (const float*)d_in[5];
    const float* b01 = (const float*)d_in[6];
    const float* W10 = (const float*)d_in[7];
    const float* b10 = (const float*)d_in[8];
    const float* W11 = (const float*)d_in[9];
    const float* b11 = (const float*)d_in[10];
    const float* W12 = (const float*)d_in[11];
    const float* b12 = (const float*)d_in[12];
    float* out = (float*)d_out;

    char* ws = (char*)d_ws;
    unsigned short* xb     = (unsigned short*)(ws);               // 64 MB
    unsigned short* s      = (unsigned short*)(ws + 67108864);    // 32 MB
    int*            nbr_eff= (int*)           (ws + 100663296);   // 27 MB
    unsigned short* w00p   = (unsigned short*)(ws + 128974848);   // 216 KB
    unsigned short* w10p   = (unsigned short*)(ws + 129196032);   // 8 KB
    unsigned short* w01p   = (unsigned short*)(ws + 129204224);   // 108 KB
    unsigned short* w11p   = (unsigned short*)(ws + 129314816);   // 54 KB
    unsigned short* w12p   = (unsigned short*)(ws + 129370112);   // 4 KB
    int*            flag   = (int*)           (ws + 129374208);

    int total_nm = NVOX * KOFF;
    k_detect<<<1, 64, 0, stream>>>((const int*)mask, flag);
    k_prepnbr<<<(total_nm + 255)/256, 256, 0, stream>>>(nbr, mask, flag, nbr_eff, total_nm);
    k_convert<<<16384, 256, 0, stream>>>(x, (uint4*)xb);
    k_pack<<<(27*128*32 + 255)/256, 256, 0, stream>>>(W00, w00p, 27, 128, 32);
    k_pack<<<(128*32    + 255)/256, 256, 0, stream>>>(W10, w10p, 1, 128, 32);
    k_pack<<<(27*32*64  + 255)/256, 256, 0, stream>>>(W01, w01p, 27, 32, 64);
    k_pack<<<(27*32*32  + 255)/256, 256, 0, stream>>>(W11, w11p, 27, 32, 32);
    k_pack<<<(32*64     + 255)/256, 256, 0, stream>>>(W12, w12p, 1, 32, 64);
    k_convA<<<NVOX/64, 256, 0, stream>>>(xb, nbr_eff, w00p, w10p, b00, b10, s);
    k_convB<<<NVOX/64, 256, 0, stream>>>(s, x, nbr_eff, w01p, w11p, w12p,
                                         b01, b11, b12, out);
}

// Round 3
// 765.634 us; speedup vs baseline: 1.0227x; 1.0227x over previous
//
#include <hip/hip_runtime.h>
#include <stdint.h>

#define NVOX 262144
#define CIN  128
#define KOFF 27

typedef short  bf16x8 __attribute__((ext_vector_type(8)));
typedef float  f32x4  __attribute__((ext_vector_type(4)));

__device__ __forceinline__ unsigned short f2bf(float x) {
    unsigned int u = __builtin_bit_cast(unsigned int, x);
    u += 0x7fff + ((u >> 16) & 1);           // round-to-nearest-even
    return (unsigned short)(u >> 16);
}

// ---- detect mask dtype: int32 (all of first 256 words in {0,1}) vs byte ----
__global__ void k_detect(const int* __restrict__ mask_i32, int* __restrict__ flag) {
    bool ok = true;
    for (int i = threadIdx.x; i < 256; i += 64) {
        int v = mask_i32[i];
        ok = ok && (v == 0 || v == 1);
    }
    unsigned long long b = __ballot(ok);
    if (threadIdx.x == 0) *flag = (b == ~0ull) ? 1 : 0;
}

// ---- fold mask into neighbor list: nbr_eff = mask ? nbr : -1 ----
__global__ __launch_bounds__(256) void k_prepnbr(
    const int* __restrict__ nbr, const void* __restrict__ mask,
    const int* __restrict__ flag, int* __restrict__ nbr_eff, int total) {
    int i = blockIdx.x * 256 + threadIdx.x;
    if (i >= total) return;
    bool mk;
    if (*flag) mk = ((const int*)mask)[i] != 0;
    else       mk = ((const unsigned char*)mask)[i] != 0;
    nbr_eff[i] = mk ? nbr[i] : -1;
}

// ---------------- prep: x (f32) -> xb (bf16), 8 elems/thread ----------------
__global__ __launch_bounds__(256) void k_convert(const float* __restrict__ x,
                                                 uint4* __restrict__ xb) {
    int i = blockIdx.x * 256 + threadIdx.x;          // one uint4 (8 bf16) out
    const float4* p = (const float4*)x + (size_t)i * 2;
    float4 a = p[0], b = p[1];
    uint4 r;
    r.x = f2bf(a.x) | ((unsigned)f2bf(a.y) << 16);
    r.y = f2bf(a.z) | ((unsigned)f2bf(a.w) << 16);
    r.z = f2bf(b.x) | ((unsigned)f2bf(b.y) << 16);
    r.w = f2bf(b.z) | ((unsigned)f2bf(b.w) << 16);
    xb[i] = r;
}

// ---------------- prep: pack weight [G,K,Nc] f32 -> MFMA B-frag bf16 --------
__global__ __launch_bounds__(256) void k_pack(const float* __restrict__ W,
                                              unsigned short* __restrict__ out,
                                              int G, int K, int Nc) {
    int idx = blockIdx.x * 256 + threadIdx.x;
    int total = G * K * Nc;
    if (idx >= total) return;
    int j    = idx & 7;
    int lane = (idx >> 3) & 63;
    int f    = idx >> 9;
    int ntiles = Nc >> 4, kcs = K >> 5;
    int g  = f / (kcs * ntiles);
    int rem = f - g * (kcs * ntiles);
    int kc = rem / ntiles;
    int nt = rem - kc * ntiles;
    int k  = kc * 32 + ((lane >> 4) << 3) + j;
    int n  = nt * 16 + (lane & 15);
    out[idx] = f2bf(W[((size_t)g * K + k) * Nc + n]);
}

// ---------------- kernel A: s = [relu(conv00(x)+b00) | relu(x@W10+b10)] -----
__global__ __launch_bounds__(256) void k_convA(
    const unsigned short* __restrict__ xb,
    const int* __restrict__ nbr_eff,
    const unsigned short* __restrict__ w00, const unsigned short* __restrict__ w10,
    const float* __restrict__ b00, const float* __restrict__ b10,
    unsigned short* __restrict__ s_out)
{
    __shared__ int nbr_s[64 * 27];
    __shared__ unsigned short stage[64 * 72];

    int tid = threadIdx.x;
    int vb  = blockIdx.x * 64;
    for (int i = tid; i < 64 * 27; i += 256)
        nbr_s[i] = nbr_eff[(size_t)vb * 27 + i];
    __syncthreads();

    int lane = tid & 63, wave = tid >> 6;
    int m = lane & 15, q = lane >> 4;
    int vl = wave * 16 + m;

    const bf16x8 zero = {0,0,0,0,0,0,0,0};
    f32x4 t0 = {0.f,0.f,0.f,0.f}, t1 = t0, u0 = t0, u1 = t0;

    bf16x8 ac[4], an[4];
    {   // prologue: gather ko=0
        int j = nbr_s[vl * 27];
        bool mk = j >= 0;
        const bf16x8* xr = (const bf16x8*)(xb + (size_t)(mk ? j : 0) * 128 + q * 8);
#pragma unroll
        for (int kc = 0; kc < 4; ++kc) ac[kc] = mk ? xr[kc * 4] : zero;
    }
#pragma unroll
    for (int ko = 0; ko < 27; ++ko) {
        if (ko < 26) {                               // prefetch ko+1 gathers
            int j = nbr_s[vl * 27 + ko + 1];
            bool mk = j >= 0;
            const bf16x8* xr = (const bf16x8*)(xb + (size_t)(mk ? j : 0) * 128 + q * 8);
#pragma unroll
            for (int kc = 0; kc < 4; ++kc) an[kc] = mk ? xr[kc * 4] : zero;
        }
        const bf16x8* wp = (const bf16x8*)(w00) + (size_t)ko * 8 * 64 + lane;
#pragma unroll
        for (int kc = 0; kc < 4; ++kc) {
            t0 = __builtin_amdgcn_mfma_f32_16x16x32_bf16(ac[kc], wp[kc * 128],      t0, 0, 0, 0);
            t1 = __builtin_amdgcn_mfma_f32_16x16x32_bf16(ac[kc], wp[kc * 128 + 64], t1, 0, 0, 0);
        }
        if (ko == 13) {                              // center offset == own row
            const bf16x8* wq = (const bf16x8*)(w10) + lane;
#pragma unroll
            for (int kc = 0; kc < 4; ++kc) {
                u0 = __builtin_amdgcn_mfma_f32_16x16x32_bf16(ac[kc], wq[kc * 128],      u0, 0, 0, 0);
                u1 = __builtin_amdgcn_mfma_f32_16x16x32_bf16(ac[kc], wq[kc * 128 + 64], u1, 0, 0, 0);
            }
        }
#pragma unroll
        for (int kc = 0; kc < 4; ++kc) ac[kc] = an[kc];
    }

    // epilogue: bias + relu -> bf16 via LDS transpose, coalesced store
    int col = lane & 15;
    float bt0 = b00[col], bt1 = b00[16 + col];
    float bu0 = b10[col], bu1 = b10[16 + col];
#pragma unroll
    for (int r = 0; r < 4; ++r) {
        int row = wave * 16 + q * 4 + r;
        unsigned short* sp = stage + row * 72;
        sp[col]      = f2bf(fmaxf(t0[r] + bt0, 0.f));
        sp[16 + col] = f2bf(fmaxf(t1[r] + bt1, 0.f));
        sp[32 + col] = f2bf(fmaxf(u0[r] + bu0, 0.f));
        sp[48 + col] = f2bf(fmaxf(u1[r] + bu1, 0.f));
    }
    __syncthreads();
    uint4* g4 = (uint4*)(s_out + (size_t)vb * 64);
    for (int i = tid; i < 512; i += 256) {
        int row = i >> 3, c = i & 7;
        g4[row * 8 + c] = *(const uint4*)(stage + row * 72 + c * 8);
    }
}

// ---------------- kernel B: out = [conv01(t)+b01 | relu(conv11(u)+b11)@W12+b12] + x
__global__ __launch_bounds__(256) void k_convB(
    const unsigned short* __restrict__ s_in,
    const float* __restrict__ x,
    const int* __restrict__ nbr_eff,
    const unsigned short* __restrict__ w01, const unsigned short* __restrict__ w11,
    const unsigned short* __restrict__ w12,
    const float* __restrict__ b01, const float* __restrict__ b11,
    const float* __restrict__ b12,
    float* __restrict__ out)
{
    __shared__ int nbr_s[64 * 27];
    __shared__ unsigned short vstage[4][16 * 40];
    __shared__ float ostage[64 * 136];

    int tid = threadIdx.x;
    int vb  = blockIdx.x * 64;
    for (int i = tid; i < 64 * 27; i += 256)
        nbr_s[i] = nbr_eff[(size_t)vb * 27 + i];
    __syncthreads();

    int lane = tid & 63, wave = tid >> 6;
    int m = lane & 15, q = lane >> 4;
    int vl = wave * 16 + m;

    const bf16x8 zero = {0,0,0,0,0,0,0,0};
    f32x4 o0 = {0.f,0.f,0.f,0.f}, o1 = o0, o2 = o0, o3 = o0, v0 = o0, v1 = o0;

    bf16x8 atc, auc, atn, aun;
    {   // prologue
        int j = nbr_s[vl * 27];
        bool mk = j >= 0;
        const bf16x8* sr = (const bf16x8*)(s_in + (size_t)(mk ? j : 0) * 64 + q * 8);
        atc = mk ? sr[0] : zero;
        auc = mk ? sr[4] : zero;
    }
#pragma unroll
    for (int ko = 0; ko < 27; ++ko) {
        if (ko < 26) {                               // prefetch ko+1
            int j = nbr_s[vl * 27 + ko + 1];
            bool mk = j >= 0;
            const bf16x8* sr = (const bf16x8*)(s_in + (size_t)(mk ? j : 0) * 64 + q * 8);
            atn = mk ? sr[0] : zero;
            aun = mk ? sr[4] : zero;
        }
        const bf16x8* wp1 = (const bf16x8*)(w01) + (size_t)ko * 4 * 64 + lane;
        o0 = __builtin_amdgcn_mfma_f32_16x16x32_bf16(atc, wp1[0],   o0, 0, 0, 0);
        o1 = __builtin_amdgcn_mfma_f32_16x16x32_bf16(atc, wp1[64],  o1, 0, 0, 0);
        o2 = __builtin_amdgcn_mfma_f32_16x16x32_bf16(atc, wp1[128], o2, 0, 0, 0);
        o3 = __builtin_amdgcn_mfma_f32_16x16x32_bf16(atc, wp1[192], o3, 0, 0, 0);
        const bf16x8* wp2 = (const bf16x8*)(w11) + (size_t)ko * 2 * 64 + lane;
        v0 = __builtin_amdgcn_mfma_f32_16x16x32_bf16(auc, wp2[0],   v0, 0, 0, 0);
        v1 = __builtin_amdgcn_mfma_f32_16x16x32_bf16(auc, wp2[64],  v1, 0, 0, 0);
        atc = atn; auc = aun;
    }

    // v = relu(v + b11): C-layout -> A-layout via LDS round-trip
    int col = lane & 15;
    {
        float bv0 = b11[col], bv1 = b11[16 + col];
        unsigned short* vs = vstage[wave];
#pragma unroll
        for (int r = 0; r < 4; ++r) {
            int row = q * 4 + r;
            vs[row * 40 + col]      = f2bf(fmaxf(v0[r] + bv0, 0.f));
            vs[row * 40 + 16 + col] = f2bf(fmaxf(v1[r] + bv1, 0.f));
        }
    }
    __syncthreads();
    bf16x8 av = *(const bf16x8*)(vstage[wave] + m * 40 + q * 8);
    const bf16x8* wp3 = (const bf16x8*)(w12) + lane;
    f32x4 z = {0.f,0.f,0.f,0.f};
    f32x4 o4 = __builtin_amdgcn_mfma_f32_16x16x32_bf16(av, wp3[0],   z, 0, 0, 0);
    f32x4 o5 = __builtin_amdgcn_mfma_f32_16x16x32_bf16(av, wp3[64],  z, 0, 0, 0);
    f32x4 o6 = __builtin_amdgcn_mfma_f32_16x16x32_bf16(av, wp3[128], z, 0, 0, 0);
    f32x4 o7 = __builtin_amdgcn_mfma_f32_16x16x32_bf16(av, wp3[192], z, 0, 0, 0);

#pragma unroll
    for (int r = 0; r < 4; ++r) {
        int row = wave * 16 + q * 4 + r;
        float* op = ostage + row * 136;
        op[col]       = o0[r] + b01[col];
        op[16 + col]  = o1[r] + b01[16 + col];
        op[32 + col]  = o2[r] + b01[32 + col];
        op[48 + col]  = o3[r] + b01[48 + col];
        op[64 + col]  = o4[r] + b12[col];
        op[80 + col]  = o5[r] + b12[16 + col];
        op[96 + col]  = o6[r] + b12[32 + col];
        op[112 + col] = o7[r] + b12[48 + col];
    }
    __syncthreads();
    for (int i = tid; i < 2048; i += 256) {
        int row = i >> 5, c4 = i & 31;
        const float* sp = ostage + row * 136 + c4 * 4;
        size_t go = ((size_t)(vb + row)) * 128 + c4 * 4;
        float4 xv = *(const float4*)(x + go);
        float4 r;
        r.x = sp[0] + xv.x; r.y = sp[1] + xv.y;
        r.z = sp[2] + xv.z; r.w = sp[3] + xv.w;
        *(float4*)(out + go) = r;
    }
}

extern "C" void kernel_launch(void* const* d_in, const int* in_sizes, int n_in,
                              void* d_out, int out_size, void* d_ws, size_t ws_size,
                              hipStream_t stream) {
    const float* x   = (const float*)d_in[0];
    const int*   nbr = (const int*)d_in[1];
    const void*  mask = d_in[2];                      // dtype detected at runtime
    const float* W00 = (const float*)d_in[3];
    const float* b00 = (const float*)d_in[4];
    const float* W01 = (const float*)d_in[5];
    const float* b01 = (const float*)d_in[6];
    const float* W10 = (const float*)d_in[7];
    const float* b10 = (const float*)d_in[8];
    const float* W11 = (const float*)d_in[9];
    const float* b11 = (const float*)d_in[10];
    const float* W12 = (const float*)d_in[11];
    const float* b12 = (const float*)d_in[12];
    float* out = (float*)d_out;

    char* ws = (char*)d_ws;
    unsigned short* xb     = (unsigned short*)(ws);               // 64 MB
    unsigned short* s      = (unsigned short*)(ws + 67108864);    // 32 MB
    int*            nbr_eff= (int*)           (ws + 100663296);   // 27 MB
    unsigned short* w00p   = (unsigned short*)(ws + 128974848);   // 216 KB
    unsigned short* w10p   = (unsigned short*)(ws + 129196032);   // 8 KB
    unsigned short* w01p   = (unsigned short*)(ws + 129204224);   // 108 KB
    unsigned short* w11p   = (unsigned short*)(ws + 129314816);   // 54 KB
    unsigned short* w12p   = (unsigned short*)(ws + 129370112);   // 4 KB
    int*            flag   = (int*)           (ws + 129374208);

    int total_nm = NVOX * KOFF;
    k_detect<<<1, 64, 0, stream>>>((const int*)mask, flag);
    k_prepnbr<<<(total_nm + 255)/256, 256, 0, stream>>>(nbr, mask, flag, nbr_eff, total_nm);
    k_convert<<<16384, 256, 0, stream>>>(x, (uint4*)xb);
    k_pack<<<(27*128*32 + 255)/256, 256, 0, stream>>>(W00, w00p, 27, 128, 32);
    k_pack<<<(128*32    + 255)/256, 256, 0, stream>>>(W10, w10p, 1, 128, 32);
    k_pack<<<(27*32*64  + 255)/256, 256, 0, stream>>>(W01, w01p, 27, 32, 64);
    k_pack<<<(27*32*32  + 255)/256, 256, 0, stream>>>(W11, w11p, 27, 32, 32);
    k_pack<<<(32*64     + 255)/256, 256, 0, stream>>>(W12, w12p, 1, 32, 64);
    k_convA<<<NVOX/64, 256, 0, stream>>>(xb, nbr_eff, w00p, w10p, b00, b10, s);
    k_convB<<<NVOX/64, 256, 0, stream>>>(s, x, nbr_eff, w01p, w11p, w12p,
                                         b01, b11, b12, out);
}

// Round 4
// 683.093 us; speedup vs baseline: 1.1463x; 1.1208x over previous
//
#include <hip/hip_runtime.h>
#include <stdint.h>

#define NVOX 262144
#define CIN  128
#define KOFF 27

typedef short  bf16x8 __attribute__((ext_vector_type(8)));
typedef float  f32x4  __attribute__((ext_vector_type(4)));

__device__ __forceinline__ unsigned short f2bf(float x) {
    unsigned int u = __builtin_bit_cast(unsigned int, x);
    u += 0x7fff + ((u >> 16) & 1);           // round-to-nearest-even
    return (unsigned short)(u >> 16);
}

// ---- detect mask dtype: int32 (all of first 256 words in {0,1}) vs byte ----
__global__ void k_detect(const int* __restrict__ mask_i32, int* __restrict__ flag) {
    bool ok = true;
    for (int i = threadIdx.x; i < 256; i += 64) {
        int v = mask_i32[i];
        ok = ok && (v == 0 || v == 1);
    }
    unsigned long long b = __ballot(ok);
    if (threadIdx.x == 0) *flag = (b == ~0ull) ? 1 : 0;
}

// ---- fold mask into neighbor list: nbr_eff = mask ? nbr : -1 ----
__global__ __launch_bounds__(256) void k_prepnbr(
    const int* __restrict__ nbr, const void* __restrict__ mask,
    const int* __restrict__ flag, int* __restrict__ nbr_eff, int total) {
    int i = blockIdx.x * 256 + threadIdx.x;
    if (i >= total) return;
    bool mk;
    if (*flag) mk = ((const int*)mask)[i] != 0;
    else       mk = ((const unsigned char*)mask)[i] != 0;
    nbr_eff[i] = mk ? nbr[i] : -1;
}

// ---------------- prep: x (f32) -> xb (bf16), 8 elems/thread ----------------
__global__ __launch_bounds__(256) void k_convert(const float* __restrict__ x,
                                                 uint4* __restrict__ xb) {
    int i = blockIdx.x * 256 + threadIdx.x;
    const float4* p = (const float4*)x + (size_t)i * 2;
    float4 a = p[0], b = p[1];
    uint4 r;
    r.x = f2bf(a.x) | ((unsigned)f2bf(a.y) << 16);
    r.y = f2bf(a.z) | ((unsigned)f2bf(a.w) << 16);
    r.z = f2bf(b.x) | ((unsigned)f2bf(b.y) << 16);
    r.w = f2bf(b.z) | ((unsigned)f2bf(b.w) << 16);
    xb[i] = r;
}

// ---------------- prep: pack weight [G,K,Nc] f32 -> MFMA B-frag bf16 --------
__global__ __launch_bounds__(256) void k_pack(const float* __restrict__ W,
                                              unsigned short* __restrict__ out,
                                              int G, int K, int Nc) {
    int idx = blockIdx.x * 256 + threadIdx.x;
    int total = G * K * Nc;
    if (idx >= total) return;
    int j    = idx & 7;
    int lane = (idx >> 3) & 63;
    int f    = idx >> 9;
    int ntiles = Nc >> 4, kcs = K >> 5;
    int g  = f / (kcs * ntiles);
    int rem = f - g * (kcs * ntiles);
    int kc = rem / ntiles;
    int nt = rem - kc * ntiles;
    int k  = kc * 32 + ((lane >> 4) << 3) + j;
    int n  = nt * 16 + (lane & 15);
    out[idx] = f2bf(W[((size_t)g * K + k) * Nc + n]);
}

// ---------------- kernel A: s = [relu(conv00(x)+b00) | relu(x@W10+b10)] -----
// 128 voxels/block, 4 waves x 32 rows (two 16-row MFMA tiles per wave)
__global__ __launch_bounds__(256) void k_convA(
    const unsigned short* __restrict__ xb,
    const int* __restrict__ nbr_eff,
    const unsigned short* __restrict__ w00, const unsigned short* __restrict__ w10,
    const float* __restrict__ b00, const float* __restrict__ b10,
    unsigned short* __restrict__ s_out)
{
    __shared__ int nbr_s[128 * 27];
    __shared__ unsigned short stage[128 * 72];

    int tid = threadIdx.x;
    // XCD-contiguous swizzle: round-robin dispatch % 8 -> give each XCD a
    // contiguous 1/8 voxel band so gathers hit its private L2.
    int lb = ((blockIdx.x & 7) << 8) | (blockIdx.x >> 3);   // 2048 blocks
    int vb = lb * 128;
    for (int i = tid; i < 128 * 27; i += 256)
        nbr_s[i] = nbr_eff[(size_t)vb * 27 + i];
    __syncthreads();

    int lane = tid & 63, wave = tid >> 6;
    int m = lane & 15, q = lane >> 4;
    int vl0 = wave * 32 + m, vl1 = vl0 + 16;

    const bf16x8 zero = {0,0,0,0,0,0,0,0};
    f32x4 zz = {0.f,0.f,0.f,0.f};
    f32x4 t00 = zz, t01 = zz, t10 = zz, t11 = zz;
    f32x4 u00 = zz, u01 = zz, u10 = zz, u11 = zz;

#pragma unroll
    for (int ko = 0; ko < 27; ++ko) {
        int j0 = nbr_s[vl0 * 27 + ko];
        int j1 = nbr_s[vl1 * 27 + ko];
        bool m0 = j0 >= 0, m1 = j1 >= 0;
        const bf16x8* xr0 = (const bf16x8*)(xb + (size_t)(m0 ? j0 : 0) * 128 + q * 8);
        const bf16x8* xr1 = (const bf16x8*)(xb + (size_t)(m1 ? j1 : 0) * 128 + q * 8);
        bf16x8 a0[4], a1[4];
#pragma unroll
        for (int kc = 0; kc < 4; ++kc) {
            a0[kc] = m0 ? xr0[kc * 4] : zero;
            a1[kc] = m1 ? xr1[kc * 4] : zero;
        }
        const bf16x8* wp = (const bf16x8*)(w00) + (size_t)ko * 8 * 64 + lane;
#pragma unroll
        for (int kc = 0; kc < 4; ++kc) {
            bf16x8 bb0 = wp[kc * 128];
            bf16x8 bb1 = wp[kc * 128 + 64];
            t00 = __builtin_amdgcn_mfma_f32_16x16x32_bf16(a0[kc], bb0, t00, 0, 0, 0);
            t01 = __builtin_amdgcn_mfma_f32_16x16x32_bf16(a0[kc], bb1, t01, 0, 0, 0);
            t10 = __builtin_amdgcn_mfma_f32_16x16x32_bf16(a1[kc], bb0, t10, 0, 0, 0);
            t11 = __builtin_amdgcn_mfma_f32_16x16x32_bf16(a1[kc], bb1, t11, 0, 0, 0);
        }
        if (ko == 13) {                              // center offset == own row
            const bf16x8* wq = (const bf16x8*)(w10) + lane;
#pragma unroll
            for (int kc = 0; kc < 4; ++kc) {
                bf16x8 c0 = wq[kc * 128];
                bf16x8 c1 = wq[kc * 128 + 64];
                u00 = __builtin_amdgcn_mfma_f32_16x16x32_bf16(a0[kc], c0, u00, 0, 0, 0);
                u01 = __builtin_amdgcn_mfma_f32_16x16x32_bf16(a0[kc], c1, u01, 0, 0, 0);
                u10 = __builtin_amdgcn_mfma_f32_16x16x32_bf16(a1[kc], c0, u10, 0, 0, 0);
                u11 = __builtin_amdgcn_mfma_f32_16x16x32_bf16(a1[kc], c1, u11, 0, 0, 0);
            }
        }
    }

    // epilogue: bias + relu -> bf16 via LDS transpose, coalesced store
    int col = lane & 15;
    float bt0 = b00[col], bt1 = b00[16 + col];
    float bu0 = b10[col], bu1 = b10[16 + col];
#pragma unroll
    for (int r = 0; r < 4; ++r) {
        int row0 = wave * 32 + q * 4 + r;
        unsigned short* sp0 = stage + row0 * 72;
        sp0[col]      = f2bf(fmaxf(t00[r] + bt0, 0.f));
        sp0[16 + col] = f2bf(fmaxf(t01[r] + bt1, 0.f));
        sp0[32 + col] = f2bf(fmaxf(u00[r] + bu0, 0.f));
        sp0[48 + col] = f2bf(fmaxf(u01[r] + bu1, 0.f));
        unsigned short* sp1 = sp0 + 16 * 72;
        sp1[col]      = f2bf(fmaxf(t10[r] + bt0, 0.f));
        sp1[16 + col] = f2bf(fmaxf(t11[r] + bt1, 0.f));
        sp1[32 + col] = f2bf(fmaxf(u10[r] + bu0, 0.f));
        sp1[48 + col] = f2bf(fmaxf(u11[r] + bu1, 0.f));
    }
    __syncthreads();
    uint4* g4 = (uint4*)(s_out + (size_t)vb * 64);
    for (int i = tid; i < 1024; i += 256) {
        int row = i >> 3, c = i & 7;
        g4[row * 8 + c] = *(const uint4*)(stage + row * 72 + c * 8);
    }
}

// ---------------- kernel B: out = [conv01(t)+b01 | relu(conv11(u)+b11)@W12+b12] + x
__global__ __launch_bounds__(256) void k_convB(
    const unsigned short* __restrict__ s_in,
    const float* __restrict__ x,
    const int* __restrict__ nbr_eff,
    const unsigned short* __restrict__ w01, const unsigned short* __restrict__ w11,
    const unsigned short* __restrict__ w12,
    const float* __restrict__ b01, const float* __restrict__ b11,
    const float* __restrict__ b12,
    float* __restrict__ out)
{
    __shared__ int nbr_s[128 * 27];
    __shared__ unsigned short vstage[4][2][16 * 40];

    int tid = threadIdx.x;
    int lb = ((blockIdx.x & 7) << 8) | (blockIdx.x >> 3);
    int vb = lb * 128;
    for (int i = tid; i < 128 * 27; i += 256)
        nbr_s[i] = nbr_eff[(size_t)vb * 27 + i];
    __syncthreads();

    int lane = tid & 63, wave = tid >> 6;
    int m = lane & 15, q = lane >> 4;
    int vl0 = wave * 32 + m, vl1 = vl0 + 16;

    const bf16x8 zero = {0,0,0,0,0,0,0,0};
    f32x4 zz = {0.f,0.f,0.f,0.f};
    f32x4 o[2][4];
    f32x4 v[2][2];
#pragma unroll
    for (int tl = 0; tl < 2; ++tl) {
        o[tl][0] = zz; o[tl][1] = zz; o[tl][2] = zz; o[tl][3] = zz;
        v[tl][0] = zz; v[tl][1] = zz;
    }

#pragma unroll
    for (int ko = 0; ko < 27; ++ko) {
        int j0 = nbr_s[vl0 * 27 + ko];
        int j1 = nbr_s[vl1 * 27 + ko];
        bool m0 = j0 >= 0, m1 = j1 >= 0;
        const bf16x8* sr0 = (const bf16x8*)(s_in + (size_t)(m0 ? j0 : 0) * 64 + q * 8);
        const bf16x8* sr1 = (const bf16x8*)(s_in + (size_t)(m1 ? j1 : 0) * 64 + q * 8);
        bf16x8 at0 = m0 ? sr0[0] : zero;
        bf16x8 au0 = m0 ? sr0[4] : zero;
        bf16x8 at1 = m1 ? sr1[0] : zero;
        bf16x8 au1 = m1 ? sr1[4] : zero;
        const bf16x8* wp1 = (const bf16x8*)(w01) + (size_t)ko * 4 * 64 + lane;
#pragma unroll
        for (int nt = 0; nt < 4; ++nt) {
            bf16x8 bb = wp1[nt * 64];
            o[0][nt] = __builtin_amdgcn_mfma_f32_16x16x32_bf16(at0, bb, o[0][nt], 0, 0, 0);
            o[1][nt] = __builtin_amdgcn_mfma_f32_16x16x32_bf16(at1, bb, o[1][nt], 0, 0, 0);
        }
        const bf16x8* wp2 = (const bf16x8*)(w11) + (size_t)ko * 2 * 64 + lane;
#pragma unroll
        for (int nt = 0; nt < 2; ++nt) {
            bf16x8 bb = wp2[nt * 64];
            v[0][nt] = __builtin_amdgcn_mfma_f32_16x16x32_bf16(au0, bb, v[0][nt], 0, 0, 0);
            v[1][nt] = __builtin_amdgcn_mfma_f32_16x16x32_bf16(au1, bb, v[1][nt], 0, 0, 0);
        }
    }

    // v = relu(v + b11): C-layout -> A-layout via LDS round-trip
    int col = lane & 15;
    {
        float bv0 = b11[col], bv1 = b11[16 + col];
#pragma unroll
        for (int tl = 0; tl < 2; ++tl) {
            unsigned short* vs = vstage[wave][tl];
#pragma unroll
            for (int r = 0; r < 4; ++r) {
                int row = q * 4 + r;
                vs[row * 40 + col]      = f2bf(fmaxf(v[tl][0][r] + bv0, 0.f));
                vs[row * 40 + 16 + col] = f2bf(fmaxf(v[tl][1][r] + bv1, 0.f));
            }
        }
    }
    __syncthreads();
    const bf16x8* wp3 = (const bf16x8*)(w12) + lane;
    bf16x8 w3[4];
#pragma unroll
    for (int nt = 0; nt < 4; ++nt) w3[nt] = wp3[nt * 64];
    f32x4 p[2][4];
#pragma unroll
    for (int tl = 0; tl < 2; ++tl) {
        bf16x8 av = *(const bf16x8*)(vstage[wave][tl] + m * 40 + q * 8);
#pragma unroll
        for (int nt = 0; nt < 4; ++nt)
            p[tl][nt] = __builtin_amdgcn_mfma_f32_16x16x32_bf16(av, w3[nt], zz, 0, 0, 0);
    }

    // direct C-layout stores: 16-lane 64B segments, residual add from x
    float bo[4], bp[4];
#pragma unroll
    for (int nt = 0; nt < 4; ++nt) { bo[nt] = b01[nt * 16 + col]; bp[nt] = b12[nt * 16 + col]; }
#pragma unroll
    for (int tl = 0; tl < 2; ++tl) {
#pragma unroll
        for (int r = 0; r < 4; ++r) {
            int row = vb + wave * 32 + tl * 16 + q * 4 + r;
            const float* xr = x + (size_t)row * 128;
            float* orow = out + (size_t)row * 128;
#pragma unroll
            for (int nt = 0; nt < 4; ++nt) {
                orow[nt * 16 + col]      = o[tl][nt][r] + bo[nt] + xr[nt * 16 + col];
                orow[64 + nt * 16 + col] = p[tl][nt][r] + bp[nt] + xr[64 + nt * 16 + col];
            }
        }
    }
}

extern "C" void kernel_launch(void* const* d_in, const int* in_sizes, int n_in,
                              void* d_out, int out_size, void* d_ws, size_t ws_size,
                              hipStream_t stream) {
    const float* x   = (const float*)d_in[0];
    const int*   nbr = (const int*)d_in[1];
    const void*  mask = d_in[2];
    const float* W00 = (const float*)d_in[3];
    const float* b00 = (const float*)d_in[4];
    const float* W01 = (const float*)d_in[5];
    const float* b01 = (const float*)d_in[6];
    const float* W10 = (const float*)d_in[7];
    const float* b10 = (const float*)d_in[8];
    const float* W11 = (const float*)d_in[9];
    const float* b11 = (const float*)d_in[10];
    const float* W12 = (const float*)d_in[11];
    const float* b12 = (const float*)d_in[12];
    float* out = (float*)d_out;

    char* ws = (char*)d_ws;
    unsigned short* xb     = (unsigned short*)(ws);               // 64 MB
    unsigned short* s      = (unsigned short*)(ws + 67108864);    // 32 MB
    int*            nbr_eff= (int*)           (ws + 100663296);   // 27 MB
    unsigned short* w00p   = (unsigned short*)(ws + 128974848);   // 216 KB
    unsigned short* w10p   = (unsigned short*)(ws + 129196032);   // 8 KB
    unsigned short* w01p   = (unsigned short*)(ws + 129204224);   // 108 KB
    unsigned short* w11p   = (unsigned short*)(ws + 129314816);   // 54 KB
    unsigned short* w12p   = (unsigned short*)(ws + 129370112);   // 4 KB
    int*            flag   = (int*)           (ws + 129374208);

    int total_nm = NVOX * KOFF;
    k_detect<<<1, 64, 0, stream>>>((const int*)mask, flag);
    k_prepnbr<<<(total_nm + 255)/256, 256, 0, stream>>>(nbr, mask, flag, nbr_eff, total_nm);
    k_convert<<<16384, 256, 0, stream>>>(x, (uint4*)xb);
    k_pack<<<(27*128*32 + 255)/256, 256, 0, stream>>>(W00, w00p, 27, 128, 32);
    k_pack<<<(128*32    + 255)/256, 256, 0, stream>>>(W10, w10p, 1, 128, 32);
    k_pack<<<(27*32*64  + 255)/256, 256, 0, stream>>>(W01, w01p, 27, 32, 64);
    k_pack<<<(27*32*32  + 255)/256, 256, 0, stream>>>(W11, w11p, 27, 32, 32);
    k_pack<<<(32*64     + 255)/256, 256, 0, stream>>>(W12, w12p, 1, 32, 64);
    k_convA<<<NVOX/128, 256, 0, stream>>>(xb, nbr_eff, w00p, w10p, b00, b10, s);
    k_convB<<<NVOX/128, 256, 0, stream>>>(s, x, nbr_eff, w01p, w11p, w12p,
                                          b01, b11, b12, out);
}